// Round 5
// baseline (203.455 us; speedup 1.0000x reference)
//
#include <hip/hip_runtime.h>
#include <hip/hip_bf16.h>
#include <stdint.h>

typedef __bf16 bf16_t;
typedef bf16_t bf16x4 __attribute__((ext_vector_type(4)));
typedef bf16_t bf16x8 __attribute__((ext_vector_type(8)));
typedef float  f32x4  __attribute__((ext_vector_type(4)));

#define B_   4
#define T_   1024
#define C_   1024
#define H_   16

__device__ __forceinline__ f32x4 mfma_bf16(bf16x8 a, bf16x8 b, f32x4 c) {
  return __builtin_amdgcn_mfma_f32_16x16x32_bf16(a, b, c, 0, 0, 0);
}

__device__ __forceinline__ void async16(const bf16_t* g, bf16_t* l) {
  __builtin_amdgcn_global_load_lds(
      (__attribute__((address_space(1))) void*)(uintptr_t)g,
      (__attribute__((address_space(3))) void*)l, 16, 0, 0);
}

// ---------------------------------------------------------------- convert
__global__ __launch_bounds__(256) void convert_f32_bf16(
    const float* __restrict__ in, bf16_t* __restrict__ out, int n4)
{
  const int i = blockIdx.x * 256 + threadIdx.x;
  if (i >= n4) return;
  const float4 v = *(const float4*)(in + (size_t)i * 4);
  bf16x4 o;
  o[0] = (bf16_t)v.x; o[1] = (bf16_t)v.y; o[2] = (bf16_t)v.z; o[3] = (bf16_t)v.w;
  *(bf16x4*)(out + (size_t)i * 4) = o;
}

// ---------------------------------------------------------------- transpose
// four 1024x1024 f32 matrices -> bf16 transposed slabs of 1M elements
__global__ __launch_bounds__(256) void transpose4_f32_bf16(
    const float* __restrict__ a0, const float* __restrict__ a1,
    const float* __restrict__ a2, const float* __restrict__ a3,
    bf16_t* __restrict__ out)
{
  __shared__ bf16_t tile[32][33];
  const int z = blockIdx.z;
  const float* in = (z == 0) ? a0 : (z == 1) ? a1 : (z == 2) ? a2 : a3;
  bf16_t* o = out + ((size_t)z << 20);
  const int n0 = blockIdx.x * 32, k0 = blockIdx.y * 32;
  const int x = threadIdx.x & 31, y4 = (threadIdx.x >> 5) * 4;
#pragma unroll
  for (int i = 0; i < 4; ++i)
    tile[y4 + i][x] = (bf16_t)in[(size_t)(k0 + y4 + i) * 1024 + n0 + x];
  __syncthreads();
#pragma unroll
  for (int i = 0; i < 4; ++i)
    o[(size_t)(n0 + y4 + i) * 1024 + k0 + x] = tile[x][y4 + i];
}

// ---------------------------------------------------------------- transpose_v
// qkvb v-slice [4096 rows][cols 2048+h*64+f] -> vT[(b*16+h)*64+f][1024 keys]
__global__ __launch_bounds__(256) void transpose_v(
    const bf16_t* __restrict__ qkvb, bf16_t* __restrict__ vT)
{
  __shared__ bf16_t tile[64][66];
  const int bid = blockIdx.x;
  const int kb = bid & 15, bh = bid >> 4;
  const int b = bh >> 4, h = bh & 15;
  const int t = threadIdx.x;
  {
    const int key = t & 63, fc = (t >> 6) * 16;
    const bf16_t* src =
        qkvb + (size_t)(b * 1024 + kb * 64 + key) * 3072 + 2048 + h * 64 + fc;
    bf16x8 v0 = *(const bf16x8*)src;
    bf16x8 v1 = *(const bf16x8*)(src + 8);
#pragma unroll
    for (int j = 0; j < 8; ++j) {
      tile[fc + j][key]     = v0[j];
      tile[fc + 8 + j][key] = v1[j];
    }
  }
  __syncthreads();
  {
    const int f = t & 63, kc = (t >> 6) * 16;
    bf16x8 o0, o1;
#pragma unroll
    for (int j = 0; j < 8; ++j) {
      o0[j] = tile[f][kc + j];
      o1[j] = tile[f][kc + 8 + j];
    }
    bf16_t* dst = vT + ((size_t)bh * 64 + f) * 1024 + kb * 64 + kc;
    *(bf16x8*)dst = o0;
    *(bf16x8*)(dst + 8) = o1;
  }
}

// ---------------------------------------------------------------- bias_eff
__global__ __launch_bounds__(256) void bias_eff_kernel(
    const float* __restrict__ cb,
    const float* __restrict__ w0, const float* __restrict__ w1,
    const float* __restrict__ w2,
    const float* __restrict__ b0, const float* __restrict__ b1,
    const float* __restrict__ b2,
    float* __restrict__ out)
{
  const int j = blockIdx.x * 256 + threadIdx.x;
  const int s = j >> 10, jj = j & 1023;
  const float* w  = (s == 0) ? w0 : (s == 1) ? w1 : w2;
  const float* sb = (s == 0) ? b0 : (s == 1) ? b1 : b2;
  const int c0 = blockIdx.y * 128;
  float acc = (blockIdx.y == 0) ? sb[jj] : 0.0f;
  for (int c = c0; c < c0 + 128; ++c)
    acc += cb[s * 1024 + c] * w[(size_t)c * 1024 + jj];
  atomicAdd(&out[j], acc);
}

// ---------------------------------------------------------------- GEMM
template <typename OT>
__global__ __launch_bounds__(256) void gemm_bt_bias(
    const bf16_t* __restrict__ A, int lda,
    const bf16_t* __restrict__ Bt, int ldb,
    const float* __restrict__ bias,
    OT* __restrict__ C, int ldc,
    int K, int nTilesN, int blocksPerMat,
    int strideA, int strideB, int strideC)
{
  __shared__ __align__(16) bf16_t As[2][128 * 32];
  __shared__ __align__(16) bf16_t Bs[2][128 * 32];
  const int s   = blockIdx.x / blocksPerMat;
  const int bid = blockIdx.x % blocksPerMat;
  A  += (size_t)s * strideA;
  Bt += (size_t)s * strideB;
  C  += (size_t)s * strideC;
  const int mt = bid / nTilesN, nt = bid % nTilesN;
  const int m0 = mt * 128, n0 = nt * 128;
  const int tid = threadIdx.x;
  const int lane = tid & 63;
  const int lr = lane & 15, lg = lane >> 4;
  const int wid = tid >> 6;
  const int wr = wid >> 1, wc = wid & 1;

  f32x4 acc[4][4];
#pragma unroll
  for (int m = 0; m < 4; ++m)
#pragma unroll
    for (int n = 0; n < 4; ++n) acc[m][n] = (f32x4){0.f, 0.f, 0.f, 0.f};

  const int nk = K >> 5;
  int cur = 0;
#pragma unroll
  for (int p = 0; p < 2; ++p) {
    int c = p * 256 + tid;
    int row = c >> 2, col = (c & 3) << 3;
    async16(A + (size_t)(m0 + row) * lda + col, &As[0][row * 32 + col]);
    async16(Bt + (size_t)(n0 + row) * ldb + col, &Bs[0][row * 32 + col]);
  }
  __syncthreads();

  for (int t = 0; t < nk; ++t) {
    if (t + 1 < nk) {
      const int k0 = (t + 1) << 5;
#pragma unroll
      for (int p = 0; p < 2; ++p) {
        int c = p * 256 + tid;
        int row = c >> 2, col = (c & 3) << 3;
        async16(A + (size_t)(m0 + row) * lda + k0 + col, &As[cur ^ 1][row * 32 + col]);
        async16(Bt + (size_t)(n0 + row) * ldb + k0 + col, &Bs[cur ^ 1][row * 32 + col]);
      }
    }
    bf16x8 af[4], bfr[4];
#pragma unroll
    for (int m = 0; m < 4; ++m)
      af[m] = *(const bf16x8*)&As[cur][(wr * 64 + m * 16 + lr) * 32 + lg * 8];
#pragma unroll
    for (int n = 0; n < 4; ++n)
      bfr[n] = *(const bf16x8*)&Bs[cur][(wc * 64 + n * 16 + lr) * 32 + lg * 8];
#pragma unroll
    for (int m = 0; m < 4; ++m)
#pragma unroll
      for (int n = 0; n < 4; ++n)
        acc[m][n] = mfma_bf16(af[m], bfr[n], acc[m][n]);
    __syncthreads();
    cur ^= 1;
  }

#pragma unroll
  for (int n = 0; n < 4; ++n) {
    const int col = n0 + wc * 64 + n * 16 + lr;
    const float bv = bias ? bias[col] : 0.0f;
#pragma unroll
    for (int m = 0; m < 4; ++m) {
      const int row = m0 + wr * 64 + m * 16 + lg * 4;
#pragma unroll
      for (int r = 0; r < 4; ++r)
        C[(size_t)(row + r) * ldc + col] = (OT)(acc[m][n][r] + bv);
    }
  }
}

// ---------------------------------------------------------------- attention
// Barrier-free flash attention. Each wave owns 16 q-rows independently.
// qkv: bf16 [4096][3072] (q@0, k@1024). vT: bf16 [(b*16+h)*64+f][1024 keys].
// Wave w of block i handles q-tile j = i + 16w (load-balanced: block work
// = 4*floor(i/4)+28 for all i). No __syncthreads anywhere.
__global__ __launch_bounds__(256) void attn_kernel(
    const bf16_t* __restrict__ qkv, const bf16_t* __restrict__ vT,
    bf16_t* __restrict__ o)
{
  __shared__ __align__(16) bf16_t Ps[4][16][72];
  const int LD = 3072;
  const bf16_t* q = qkv;
  const bf16_t* k = qkv + 1024;

  const int bid = blockIdx.x;
  const int i  = bid & 15;
  const int bh = bid >> 4;            // b*16 + h
  const int b  = bh >> 4, h = bh & 15;
  const int tid = threadIdx.x;
  const int lane = tid & 63;
  const int lr = lane & 15, lg = lane >> 4;
  const int w = tid >> 6;

  const int j = i + 16 * w;           // this wave's q-tile (16 rows)
  const int myq = j * 16 + lr;
  const int nIter = (j >> 2) + 1;     // kv tiles of 64 keys

  const bf16_t* kbase = k + (size_t)(b * T_) * LD + h * 64;
  const bf16_t* vbase = vT + (size_t)bh * 64 * T_;

  bf16x8 qf[2];
  {
    const size_t qr = (size_t)(b * T_ + myq) * LD + h * 64;
    qf[0] = *(const bf16x8*)&q[qr + lg * 8];
    qf[1] = *(const bf16x8*)&q[qr + 32 + lg * 8];
  }

  float mi = -3.0e38f, li = 0.0f;
  f32x4 acc[4];
#pragma unroll
  for (int nf = 0; nf < 4; ++nf) acc[nf] = (f32x4){0.f, 0.f, 0.f, 0.f};

  for (int it = 0; it < nIter; ++it) {
    const int kv0 = it << 6;

    // S^T fragment: lane holds S[q=myq][key=kv0+kg*16+lg*4+r]
    f32x4 s[4];
#pragma unroll
    for (int kg = 0; kg < 4; ++kg) {
      f32x4 z = (f32x4){0.f, 0.f, 0.f, 0.f};
#pragma unroll
      for (int kk = 0; kk < 2; ++kk) {
        bf16x8 kf = *(const bf16x8*)
            &kbase[(size_t)(kv0 + kg * 16 + lr) * LD + kk * 32 + lg * 8];
        z = mfma_bf16(kf, qf[kk], z);
      }
      s[kg] = z;
    }

    // scale (net 1/64), causal mask, lane-local online softmax (2 shfls)
    float sv[4][4];
    float pmax = -3.0e38f;
#pragma unroll
    for (int kg = 0; kg < 4; ++kg) {
      const int keyb = kv0 + kg * 16 + lg * 4;
#pragma unroll
      for (int r = 0; r < 4; ++r) {
        float xx = s[kg][r] * 0.015625f;
        if (keyb + r > myq) xx = -3.0e38f;
        sv[kg][r] = xx;
        pmax = fmaxf(pmax, xx);
      }
    }
    pmax = fmaxf(pmax, __shfl_xor(pmax, 16));
    pmax = fmaxf(pmax, __shfl_xor(pmax, 32));
    const float mnew = fmaxf(mi, pmax);
    const float fr = __expf(mi - mnew);
    mi = mnew;
    float psum = 0.0f;
#pragma unroll
    for (int kg = 0; kg < 4; ++kg)
#pragma unroll
      for (int r = 0; r < 4; ++r) {
        const float pp = __expf(sv[kg][r] - mi);
        sv[kg][r] = pp;
        psum += pp;
      }
    psum += __shfl_xor(psum, 16);
    psum += __shfl_xor(psum, 32);
    li = li * fr + psum;
#pragma unroll
    for (int nf = 0; nf < 4; ++nf)
#pragma unroll
      for (int r = 0; r < 4; ++r) acc[nf][r] *= fr;

    // P -> LDS (b64 packed), within-wave round trip (no barrier)
#pragma unroll
    for (int kg = 0; kg < 4; ++kg) {
      bf16x4 p4;
#pragma unroll
      for (int r = 0; r < 4; ++r) p4[r] = (bf16_t)sv[kg][r];
      *(bf16x4*)&Ps[w][lr][kg * 16 + lg * 4] = p4;
    }

    // O^T += V^T @ P^T ; V^T fragments straight from global (L2/L3)
#pragma unroll
    for (int kk = 0; kk < 2; ++kk) {
      bf16x8 pf = *(const bf16x8*)&Ps[w][lr][kk * 32 + lg * 8];
#pragma unroll
      for (int nf = 0; nf < 4; ++nf) {
        bf16x8 vf = *(const bf16x8*)
            &vbase[(size_t)(nf * 16 + lr) * T_ + kv0 + kk * 32 + lg * 8];
        acc[nf] = mfma_bf16(vf, pf, acc[nf]);
      }
    }
  }

  // acc[nf][r] = O[q=myq][h*64 + nf*16 + lg*4 + r]
  const float inv = 1.0f / li;
#pragma unroll
  for (int nf = 0; nf < 4; ++nf) {
    bf16x4 o4;
#pragma unroll
    for (int r = 0; r < 4; ++r) o4[r] = (bf16_t)(acc[nf][r] * inv);
    *(bf16x4*)&o[(size_t)(b * T_ + myq) * C_ + h * 64 + nf * 16 + lg * 4] = o4;
  }
}

// ---------------------------------------------------------------- layernorm
__global__ __launch_bounds__(256) void ln_kernel(
    const bf16_t* __restrict__ in,
    const float* __restrict__ g,
    const float* __restrict__ be,
    bf16_t* __restrict__ out)
{
  const int row = blockIdx.x * 4 + (threadIdx.x >> 6);
  const int lane = threadIdx.x & 63;
  const bf16_t* p = in + (size_t)row * C_ + lane * 16;
  bf16x8 a0 = *(const bf16x8*)p;
  bf16x8 a1 = *(const bf16x8*)(p + 8);
  float xs[16];
#pragma unroll
  for (int j = 0; j < 8; ++j) { xs[j] = (float)a0[j]; xs[8 + j] = (float)a1[j]; }
  float sum = 0.f, sq = 0.f;
#pragma unroll
  for (int j = 0; j < 16; ++j) { sum += xs[j]; sq += xs[j] * xs[j]; }
#pragma unroll
  for (int dd = 1; dd < 64; dd <<= 1) {
    sum += __shfl_xor(sum, dd);
    sq  += __shfl_xor(sq, dd);
  }
  const float mean = sum * (1.0f / 1024.0f);
  const float var  = sq * (1.0f / 1024.0f) - mean * mean;
  const float rstd = rsqrtf(var + 1e-5f);
  float gv[16], bv[16];
#pragma unroll
  for (int j = 0; j < 4; ++j) {
    *(float4*)&gv[j * 4] = *(const float4*)(g  + lane * 16 + j * 4);
    *(float4*)&bv[j * 4] = *(const float4*)(be + lane * 16 + j * 4);
  }
  bf16x8 o0, o1;
#pragma unroll
  for (int j = 0; j < 8; ++j) {
    o0[j] = (bf16_t)((xs[j] - mean) * rstd * gv[j] + bv[j]);
    o1[j] = (bf16_t)((xs[8 + j] - mean) * rstd * gv[8 + j] + bv[8 + j]);
  }
  bf16_t* op = out + (size_t)row * C_ + lane * 16;
  *(bf16x8*)op = o0;
  *(bf16x8*)(op + 8) = o1;
}

// ---------------------------------------------------------------- launch
extern "C" void kernel_launch(void* const* d_in, const int* in_sizes, int n_in,
                              void* d_out, int out_size, void* d_ws, size_t ws_size,
                              hipStream_t stream)
{
  const float* x        = (const float*)d_in[0];
  const float* c_attn_w = (const float*)d_in[1];
  const float* c_attn_b = (const float*)d_in[2];
  const float* q_w      = (const float*)d_in[3];
  const float* q_b      = (const float*)d_in[4];
  const float* k_w      = (const float*)d_in[5];
  const float* k_b      = (const float*)d_in[6];
  const float* v_w      = (const float*)d_in[7];
  const float* v_b      = (const float*)d_in[8];
  const float* ln_g     = (const float*)d_in[9];
  const float* ln_b     = (const float*)d_in[10];
  const float* out_w    = (const float*)d_in[11];
  const float* out_b    = (const float*)d_in[12];

  // workspace layout (~60 MiB; earlier rounds ran cleanly at ~82 MB):
  char* ws = (char*)d_ws;
  bf16_t* qkvb      = (bf16_t*)(ws + 0);          // [4096][3072]
  bf16_t* xb        = (bf16_t*)(ws + 25165824);   // [4096][1024] dead after qkv
  bf16_t* lnb       = (bf16_t*)(ws + 25165824);   // overlays xb, used late
  bf16_t* WsT4      = (bf16_t*)(ws + 33554432);   // 4 slabs of 1M bf16
  bf16_t* c_attn_wb = (bf16_t*)(ws + 41943040);   // [1024][3072]
  bf16_t* Wt_eff    = (bf16_t*)(ws + 48234496);   // [3072][1024]
  float*  bias_eff  = (float*)(ws + 54525952);    // [3072]
  bf16_t* vT        = (bf16_t*)(ws + 54538240);   // [64*64][1024] = 8 MB

  // ingest conversions
  convert_f32_bf16<<<dim3(4096), 256, 0, stream>>>(x, xb, 1048576);
  convert_f32_bf16<<<dim3(3072), 256, 0, stream>>>(c_attn_w, c_attn_wb, 786432);

  // transposes: WsT4 slabs = {q_w^T, k_w^T, v_w^T, out_w^T} (bf16)
  transpose4_f32_bf16<<<dim3(32, 32, 4), 256, 0, stream>>>(
      q_w, k_w, v_w, out_w, WsT4);

  // fused weights: Wt_eff[s][j][c] = sum_m WsT4[s][j][m] * c_attn_wb[c][s*1024+m]
  gemm_bt_bias<bf16_t><<<dim3(192), 256, 0, stream>>>(
      WsT4, 1024, c_attn_wb, 3072, nullptr, Wt_eff, 1024,
      1024, 8, 64, 1 << 20, 1024, 1 << 20);

  // effective bias
  hipMemsetAsync(bias_eff, 0, 3072 * sizeof(float), stream);
  bias_eff_kernel<<<dim3(12, 8), 256, 0, stream>>>(
      c_attn_b, q_w, k_w, v_w, q_b, k_b, v_b, bias_eff);

  // qkvb = xb @ Wt_eff^T + bias_eff   [4096][3072]
  gemm_bt_bias<bf16_t><<<dim3(768), 256, 0, stream>>>(
      xb, 1024, Wt_eff, 1024, bias_eff, qkvb, 3072, 1024, 24, 768, 0, 0, 0);

  // V^T for barrier-free attention
  transpose_v<<<dim3(1024), 256, 0, stream>>>(qkvb, vT);

  // attention -> d_out used as bf16 scratch (fully overwritten later)
  attn_kernel<<<dim3(1024), 256, 0, stream>>>(qkvb, vT, (bf16_t*)d_out);

  // layernorm -> lnb
  ln_kernel<<<dim3(1024), 256, 0, stream>>>((const bf16_t*)d_out, ln_g, ln_b, lnb);

  // final: d_out(f32) = lnb @ out_w^T(slab 3) + out_b
  gemm_bt_bias<float><<<dim3(256), 256, 0, stream>>>(
      lnb, 1024, WsT4 + (size_t)3 * (1 << 20), 1024, out_b,
      (float*)d_out, 1024, 1024, 8, 256, 0, 0, 0);
}

// Round 6
// 190.217 us; speedup vs baseline: 1.0696x; 1.0696x over previous
//
#include <hip/hip_runtime.h>
#include <hip/hip_bf16.h>
#include <stdint.h>

typedef __bf16 bf16_t;
typedef bf16_t bf16x4 __attribute__((ext_vector_type(4)));
typedef bf16_t bf16x8 __attribute__((ext_vector_type(8)));
typedef float  f32x4  __attribute__((ext_vector_type(4)));

#define B_   4
#define T_   1024
#define C_   1024
#define H_   16

__device__ __forceinline__ f32x4 mfma_bf16(bf16x8 a, bf16x8 b, f32x4 c) {
  return __builtin_amdgcn_mfma_f32_16x16x32_bf16(a, b, c, 0, 0, 0);
}

__device__ __forceinline__ void async16(const bf16_t* g, bf16_t* l) {
  __builtin_amdgcn_global_load_lds(
      (__attribute__((address_space(1))) void*)(uintptr_t)g,
      (__attribute__((address_space(3))) void*)l, 16, 0, 0);
}

// ---------------------------------------------------------------- convert
__global__ __launch_bounds__(256) void convert_f32_bf16(
    const float* __restrict__ in, bf16_t* __restrict__ out, int n4)
{
  const int i = blockIdx.x * 256 + threadIdx.x;
  if (i >= n4) return;
  const float4 v = *(const float4*)(in + (size_t)i * 4);
  bf16x4 o;
  o[0] = (bf16_t)v.x; o[1] = (bf16_t)v.y; o[2] = (bf16_t)v.z; o[3] = (bf16_t)v.w;
  *(bf16x4*)(out + (size_t)i * 4) = o;
}

// ---------------------------------------------------------------- transpose
__global__ __launch_bounds__(256) void transpose4_f32_bf16(
    const float* __restrict__ a0, const float* __restrict__ a1,
    const float* __restrict__ a2, const float* __restrict__ a3,
    bf16_t* __restrict__ out)
{
  __shared__ bf16_t tile[32][33];
  const int z = blockIdx.z;
  const float* in = (z == 0) ? a0 : (z == 1) ? a1 : (z == 2) ? a2 : a3;
  bf16_t* o = out + ((size_t)z << 20);
  const int n0 = blockIdx.x * 32, k0 = blockIdx.y * 32;
  const int x = threadIdx.x & 31, y4 = (threadIdx.x >> 5) * 4;
#pragma unroll
  for (int i = 0; i < 4; ++i)
    tile[y4 + i][x] = (bf16_t)in[(size_t)(k0 + y4 + i) * 1024 + n0 + x];
  __syncthreads();
#pragma unroll
  for (int i = 0; i < 4; ++i)
    o[(size_t)(n0 + y4 + i) * 1024 + k0 + x] = tile[x][y4 + i];
}

// ---------------------------------------------------------------- transpose_v
__global__ __launch_bounds__(256) void transpose_v(
    const bf16_t* __restrict__ qkvb, bf16_t* __restrict__ vT)
{
  __shared__ bf16_t tile[64][66];
  const int bid = blockIdx.x;
  const int kb = bid & 15, bh = bid >> 4;
  const int b = bh >> 4, h = bh & 15;
  const int t = threadIdx.x;
  {
    const int key = t & 63, fc = (t >> 6) * 16;
    const bf16_t* src =
        qkvb + (size_t)(b * 1024 + kb * 64 + key) * 3072 + 2048 + h * 64 + fc;
    bf16x8 v0 = *(const bf16x8*)src;
    bf16x8 v1 = *(const bf16x8*)(src + 8);
#pragma unroll
    for (int j = 0; j < 8; ++j) {
      tile[fc + j][key]     = v0[j];
      tile[fc + 8 + j][key] = v1[j];
    }
  }
  __syncthreads();
  {
    const int f = t & 63, kc = (t >> 6) * 16;
    bf16x8 o0, o1;
#pragma unroll
    for (int j = 0; j < 8; ++j) {
      o0[j] = tile[f][kc + j];
      o1[j] = tile[f][kc + 8 + j];
    }
    bf16_t* dst = vT + ((size_t)bh * 64 + f) * 1024 + kb * 64 + kc;
    *(bf16x8*)dst = o0;
    *(bf16x8*)(dst + 8) = o1;
  }
}

// ---------------------------------------------------------------- bias_eff
__global__ __launch_bounds__(256) void bias_eff_kernel(
    const float* __restrict__ cb,
    const float* __restrict__ w0, const float* __restrict__ w1,
    const float* __restrict__ w2,
    const float* __restrict__ b0, const float* __restrict__ b1,
    const float* __restrict__ b2,
    float* __restrict__ out)
{
  const int j = blockIdx.x * 256 + threadIdx.x;
  const int s = j >> 10, jj = j & 1023;
  const float* w  = (s == 0) ? w0 : (s == 1) ? w1 : w2;
  const float* sb = (s == 0) ? b0 : (s == 1) ? b1 : b2;
  const int c0 = blockIdx.y * 128;
  float acc = (blockIdx.y == 0) ? sb[jj] : 0.0f;
  for (int c = c0; c < c0 + 128; ++c)
    acc += cb[s * 1024 + c] * w[(size_t)c * 1024 + jj];
  atomicAdd(&out[j], acc);
}

// ---------------------------------------------------------------- GEMM
template <typename OT>
__global__ __launch_bounds__(256) void gemm_bt_bias(
    const bf16_t* __restrict__ A, int lda,
    const bf16_t* __restrict__ Bt, int ldb,
    const float* __restrict__ bias,
    OT* __restrict__ C, int ldc,
    int K, int nTilesN, int blocksPerMat,
    int strideA, int strideB, int strideC)
{
  __shared__ __align__(16) bf16_t As[2][128 * 32];
  __shared__ __align__(16) bf16_t Bs[2][128 * 32];
  const int s   = blockIdx.x / blocksPerMat;
  const int bid = blockIdx.x % blocksPerMat;
  A  += (size_t)s * strideA;
  Bt += (size_t)s * strideB;
  C  += (size_t)s * strideC;
  const int mt = bid / nTilesN, nt = bid % nTilesN;
  const int m0 = mt * 128, n0 = nt * 128;
  const int tid = threadIdx.x;
  const int lane = tid & 63;
  const int lr = lane & 15, lg = lane >> 4;
  const int wid = tid >> 6;
  const int wr = wid >> 1, wc = wid & 1;

  f32x4 acc[4][4];
#pragma unroll
  for (int m = 0; m < 4; ++m)
#pragma unroll
    for (int n = 0; n < 4; ++n) acc[m][n] = (f32x4){0.f, 0.f, 0.f, 0.f};

  const int nk = K >> 5;
  int cur = 0;
#pragma unroll
  for (int p = 0; p < 2; ++p) {
    int c = p * 256 + tid;
    int row = c >> 2, col = (c & 3) << 3;
    async16(A + (size_t)(m0 + row) * lda + col, &As[0][row * 32 + col]);
    async16(Bt + (size_t)(n0 + row) * ldb + col, &Bs[0][row * 32 + col]);
  }
  __syncthreads();

  for (int t = 0; t < nk; ++t) {
    if (t + 1 < nk) {
      const int k0 = (t + 1) << 5;
#pragma unroll
      for (int p = 0; p < 2; ++p) {
        int c = p * 256 + tid;
        int row = c >> 2, col = (c & 3) << 3;
        async16(A + (size_t)(m0 + row) * lda + k0 + col, &As[cur ^ 1][row * 32 + col]);
        async16(Bt + (size_t)(n0 + row) * ldb + k0 + col, &Bs[cur ^ 1][row * 32 + col]);
      }
    }
    bf16x8 af[4], bfr[4];
#pragma unroll
    for (int m = 0; m < 4; ++m)
      af[m] = *(const bf16x8*)&As[cur][(wr * 64 + m * 16 + lr) * 32 + lg * 8];
#pragma unroll
    for (int n = 0; n < 4; ++n)
      bfr[n] = *(const bf16x8*)&Bs[cur][(wc * 64 + n * 16 + lr) * 32 + lg * 8];
#pragma unroll
    for (int m = 0; m < 4; ++m)
#pragma unroll
      for (int n = 0; n < 4; ++n)
        acc[m][n] = mfma_bf16(af[m], bfr[n], acc[m][n]);
    __syncthreads();
    cur ^= 1;
  }

#pragma unroll
  for (int n = 0; n < 4; ++n) {
    const int col = n0 + wc * 64 + n * 16 + lr;
    const float bv = bias ? bias[col] : 0.0f;
#pragma unroll
    for (int m = 0; m < 4; ++m) {
      const int row = m0 + wr * 64 + m * 16 + lg * 4;
#pragma unroll
      for (int r = 0; r < 4; ++r)
        C[(size_t)(row + r) * ldc + col] = (OT)(acc[m][n][r] + bv);
    }
  }
}

// ---------------------------------------------------------------- attention
// Pair-balanced barrier-free flash attention. 512 blocks x 4 waves.
// Wave task s in [0,32) of (b,h): processes q-tiles j=s AND j=63-s
// (total iters ~= 17 for every wave -> flat occupancy, no drain tail).
// All 16 fragment loads (K + V^T) issued at iteration top for max ILP.
__global__ __launch_bounds__(256) void attn_kernel(
    const bf16_t* __restrict__ qkv, const bf16_t* __restrict__ vT,
    bf16_t* __restrict__ o)
{
  __shared__ __align__(16) bf16_t Ps[4][16][72];
  const int LD = 3072;
  const bf16_t* q = qkv;
  const bf16_t* k = qkv + 1024;

  const int bid = blockIdx.x;
  const int tid = threadIdx.x;
  const int lane = tid & 63;
  const int lr = lane & 15, lg = lane >> 4;
  const int w = tid >> 6;

  const int bh = bid >> 3;                 // b*16 + h
  const int s  = (bid & 7) * 4 + w;        // wave task in [0,32)
  const int b  = bh >> 4, h = bh & 15;

  const bf16_t* kbase = k + (size_t)(b * T_) * LD + h * 64;
  const bf16_t* vbase = vT + (size_t)bh * 64 * T_;

#pragma unroll
  for (int pass = 0; pass < 2; ++pass) {
    const int j = pass ? (63 - s) : s;     // q-tile (16 rows)
    const int myq = j * 16 + lr;
    const int nIter = (j >> 2) + 1;

    bf16x8 qf[2];
    {
      const size_t qr = (size_t)(b * T_ + myq) * LD + h * 64;
      qf[0] = *(const bf16x8*)&q[qr + lg * 8];
      qf[1] = *(const bf16x8*)&q[qr + 32 + lg * 8];
    }

    float mi = -3.0e38f, li = 0.0f;
    f32x4 acc[4];
#pragma unroll
    for (int nf = 0; nf < 4; ++nf) acc[nf] = (f32x4){0.f, 0.f, 0.f, 0.f};

    for (int it = 0; it < nIter; ++it) {
      const int kv0 = it << 6;

      // issue ALL fragment loads up front (16 KB/wave in flight)
      bf16x8 kf[4][2], vf[2][4];
#pragma unroll
      for (int kg = 0; kg < 4; ++kg)
#pragma unroll
        for (int kk = 0; kk < 2; ++kk)
          kf[kg][kk] = *(const bf16x8*)
              &kbase[(size_t)(kv0 + kg * 16 + lr) * LD + kk * 32 + lg * 8];
#pragma unroll
      for (int kk = 0; kk < 2; ++kk)
#pragma unroll
        for (int nf = 0; nf < 4; ++nf)
          vf[kk][nf] = *(const bf16x8*)
              &vbase[(size_t)(nf * 16 + lr) * T_ + kv0 + kk * 32 + lg * 8];

      // S^T: lane holds S[q=myq][key=kv0+kg*16+lg*4+r]
      f32x4 sfr[4];
      __builtin_amdgcn_s_setprio(1);
#pragma unroll
      for (int kg = 0; kg < 4; ++kg) {
        f32x4 z = (f32x4){0.f, 0.f, 0.f, 0.f};
        z = mfma_bf16(kf[kg][0], qf[0], z);
        z = mfma_bf16(kf[kg][1], qf[1], z);
        sfr[kg] = z;
      }
      __builtin_amdgcn_s_setprio(0);

      // scale (net 1/64), causal mask, lane-local online softmax
      float sv[4][4];
      float pmax = -3.0e38f;
#pragma unroll
      for (int kg = 0; kg < 4; ++kg) {
        const int keyb = kv0 + kg * 16 + lg * 4;
#pragma unroll
        for (int r = 0; r < 4; ++r) {
          float xx = sfr[kg][r] * 0.015625f;
          if (keyb + r > myq) xx = -3.0e38f;
          sv[kg][r] = xx;
          pmax = fmaxf(pmax, xx);
        }
      }
      pmax = fmaxf(pmax, __shfl_xor(pmax, 16));
      pmax = fmaxf(pmax, __shfl_xor(pmax, 32));
      const float mnew = fmaxf(mi, pmax);
      const float fr = __expf(mi - mnew);
      mi = mnew;
      float psum = 0.0f;
#pragma unroll
      for (int kg = 0; kg < 4; ++kg)
#pragma unroll
        for (int r = 0; r < 4; ++r) {
          const float pp = __expf(sv[kg][r] - mi);
          sv[kg][r] = pp;
          psum += pp;
        }
      psum += __shfl_xor(psum, 16);
      psum += __shfl_xor(psum, 32);
      li = li * fr + psum;
#pragma unroll
      for (int nf = 0; nf < 4; ++nf)
#pragma unroll
        for (int r = 0; r < 4; ++r) acc[nf][r] *= fr;

      // P -> LDS (b64 packed), within-wave round trip (no barrier)
#pragma unroll
      for (int kg = 0; kg < 4; ++kg) {
        bf16x4 p4;
#pragma unroll
        for (int r = 0; r < 4; ++r) p4[r] = (bf16_t)sv[kg][r];
        *(bf16x4*)&Ps[w][lr][kg * 16 + lg * 4] = p4;
      }

      // O^T += V^T @ P^T
      __builtin_amdgcn_s_setprio(1);
#pragma unroll
      for (int kk = 0; kk < 2; ++kk) {
        bf16x8 pf = *(const bf16x8*)&Ps[w][lr][kk * 32 + lg * 8];
#pragma unroll
        for (int nf = 0; nf < 4; ++nf)
          acc[nf] = mfma_bf16(vf[kk][nf], pf, acc[nf]);
      }
      __builtin_amdgcn_s_setprio(0);
    }

    const float inv = 1.0f / li;
#pragma unroll
    for (int nf = 0; nf < 4; ++nf) {
      bf16x4 o4;
#pragma unroll
      for (int r = 0; r < 4; ++r) o4[r] = (bf16_t)(acc[nf][r] * inv);
      *(bf16x4*)&o[(size_t)(b * T_ + myq) * C_ + h * 64 + nf * 16 + lg * 4] = o4;
    }
  }
}

// ---------------------------------------------------------------- layernorm
__global__ __launch_bounds__(256) void ln_kernel(
    const bf16_t* __restrict__ in,
    const float* __restrict__ g,
    const float* __restrict__ be,
    bf16_t* __restrict__ out)
{
  const int row = blockIdx.x * 4 + (threadIdx.x >> 6);
  const int lane = threadIdx.x & 63;
  const bf16_t* p = in + (size_t)row * C_ + lane * 16;
  bf16x8 a0 = *(const bf16x8*)p;
  bf16x8 a1 = *(const bf16x8*)(p + 8);
  float xs[16];
#pragma unroll
  for (int j = 0; j < 8; ++j) { xs[j] = (float)a0[j]; xs[8 + j] = (float)a1[j]; }
  float sum = 0.f, sq = 0.f;
#pragma unroll
  for (int j = 0; j < 16; ++j) { sum += xs[j]; sq += xs[j] * xs[j]; }
#pragma unroll
  for (int dd = 1; dd < 64; dd <<= 1) {
    sum += __shfl_xor(sum, dd);
    sq  += __shfl_xor(sq, dd);
  }
  const float mean = sum * (1.0f / 1024.0f);
  const float var  = sq * (1.0f / 1024.0f) - mean * mean;
  const float rstd = rsqrtf(var + 1e-5f);
  float gv[16], bv[16];
#pragma unroll
  for (int j = 0; j < 4; ++j) {
    *(float4*)&gv[j * 4] = *(const float4*)(g  + lane * 16 + j * 4);
    *(float4*)&bv[j * 4] = *(const float4*)(be + lane * 16 + j * 4);
  }
  bf16x8 o0, o1;
#pragma unroll
  for (int j = 0; j < 8; ++j) {
    o0[j] = (bf16_t)((xs[j] - mean) * rstd * gv[j] + bv[j]);
    o1[j] = (bf16_t)((xs[8 + j] - mean) * rstd * gv[8 + j] + bv[8 + j]);
  }
  bf16_t* op = out + (size_t)row * C_ + lane * 16;
  *(bf16x8*)op = o0;
  *(bf16x8*)(op + 8) = o1;
}

// ---------------------------------------------------------------- launch
extern "C" void kernel_launch(void* const* d_in, const int* in_sizes, int n_in,
                              void* d_out, int out_size, void* d_ws, size_t ws_size,
                              hipStream_t stream)
{
  const float* x        = (const float*)d_in[0];
  const float* c_attn_w = (const float*)d_in[1];
  const float* c_attn_b = (const float*)d_in[2];
  const float* q_w      = (const float*)d_in[3];
  const float* q_b      = (const float*)d_in[4];
  const float* k_w      = (const float*)d_in[5];
  const float* k_b      = (const float*)d_in[6];
  const float* v_w      = (const float*)d_in[7];
  const float* v_b      = (const float*)d_in[8];
  const float* ln_g     = (const float*)d_in[9];
  const float* ln_b     = (const float*)d_in[10];
  const float* out_w    = (const float*)d_in[11];
  const float* out_b    = (const float*)d_in[12];

  char* ws = (char*)d_ws;
  bf16_t* qkvb      = (bf16_t*)(ws + 0);          // [4096][3072]
  bf16_t* xb        = (bf16_t*)(ws + 25165824);   // [4096][1024] dead after qkv
  bf16_t* lnb       = (bf16_t*)(ws + 25165824);   // overlays xb, used late
  bf16_t* WsT4      = (bf16_t*)(ws + 33554432);   // 4 slabs of 1M bf16
  bf16_t* c_attn_wb = (bf16_t*)(ws + 41943040);   // [1024][3072]
  bf16_t* Wt_eff    = (bf16_t*)(ws + 48234496);   // [3072][1024]
  float*  bias_eff  = (float*)(ws + 54525952);    // [3072]
  bf16_t* vT        = (bf16_t*)(ws + 54538240);   // [64*64][1024] = 8 MB

  convert_f32_bf16<<<dim3(4096), 256, 0, stream>>>(x, xb, 1048576);
  convert_f32_bf16<<<dim3(3072), 256, 0, stream>>>(c_attn_w, c_attn_wb, 786432);

  transpose4_f32_bf16<<<dim3(32, 32, 4), 256, 0, stream>>>(
      q_w, k_w, v_w, out_w, WsT4);

  gemm_bt_bias<bf16_t><<<dim3(192), 256, 0, stream>>>(
      WsT4, 1024, c_attn_wb, 3072, nullptr, Wt_eff, 1024,
      1024, 8, 64, 1 << 20, 1024, 1 << 20);

  hipMemsetAsync(bias_eff, 0, 3072 * sizeof(float), stream);
  bias_eff_kernel<<<dim3(12, 8), 256, 0, stream>>>(
      c_attn_b, q_w, k_w, v_w, q_b, k_b, v_b, bias_eff);

  gemm_bt_bias<bf16_t><<<dim3(768), 256, 0, stream>>>(
      xb, 1024, Wt_eff, 1024, bias_eff, qkvb, 3072, 1024, 24, 768, 0, 0, 0);

  transpose_v<<<dim3(1024), 256, 0, stream>>>(qkvb, vT);

  attn_kernel<<<dim3(512), 256, 0, stream>>>(qkvb, vT, (bf16_t*)d_out);

  ln_kernel<<<dim3(1024), 256, 0, stream>>>((const bf16_t*)d_out, ln_g, ln_b, lnb);

  gemm_bt_bias<float><<<dim3(256), 256, 0, stream>>>(
      lnb, 1024, WsT4 + (size_t)3 * (1 << 20), 1024, out_b,
      (float*)d_out, 1024, 1024, 8, 256, 0, 0, 0);
}